// Round 5
// baseline (960.176 us; speedup 1.0000x reference)
//
#include <hip/hip_runtime.h>

#define S2CAP 24576   // cap on |S2| (robots + sources of robot in-edges); expected ~17.4K
#define DEG   96      // padded per-node in-degree cap (Poisson(16): P(>96) ~ 1e-40)

typedef float f32x4 __attribute__((ext_vector_type(4)));

__device__ __forceinline__ float fsig(float x){ return 1.f/(1.f + __expf(-x)); }
__device__ __forceinline__ float ftanh(float a){
  a = fminf(fmaxf(a, -15.f), 15.f);
  float e2 = __expf(2.f*a);
  return (e2 - 1.f)/(e2 + 1.f);
}
__device__ __forceinline__ float attw(float e){        // leaky_relu(0.2) then exp (no max-sub)
  e = (e > 0.f) ? e : 0.2f*e;
  return __expf(e);
}

// ---- fused init: AsAd precompute + robot flag + cnt1 zero + ctrl ----
// (sidx was memset to -1 earlier in the stream)
__global__ void k_init(const float* __restrict__ c1W, const float* __restrict__ c1as,
                       const float* __restrict__ c1ad, float* __restrict__ AsAd,
                       const int* __restrict__ rix, int B, int* __restrict__ sidx,
                       int* __restrict__ nodeof, int* __restrict__ ctrl,
                       int* __restrict__ cnt1){
  int gid = blockIdx.x*blockDim.x + threadIdx.x;
  if (gid == 0) ctrl[0] = B;
  if (gid < 48){
    int which = gid/24, r = gid%24, k = r/6, h = r%6;
    const float* av = which ? c1ad : c1as;
    float s = 0.f;
    for (int f = 0; f < 16; ++f) s += c1W[(h*16+f)*4 + k] * av[h*16+f];
    AsAd[which*24 + k*6 + h] = s;
  }
  if (gid < B){ int r = rix[gid]; sidx[r] = gid; nodeof[gid] = r; }
  if (gid < S2CAP) cnt1[gid] = 0;
}

// ---- scan 1: claim sources of edges into robots ----
__global__ void k_claim(const int* __restrict__ ei, int E, int B,
                        int* __restrict__ sidx, int* __restrict__ nodeof,
                        int* __restrict__ ctrl){
  int e = blockIdx.x*blockDim.x + threadIdx.x;
  if (e >= E) return;
  int d = ei[E + e];
  int sd = sidx[d];
  if (sd < 0 || sd >= B) return;           // dst not a robot
  int s = ei[e];
  if (sidx[s] < 0){
    int old = atomicCAS(&sidx[s], -1, -2);
    if (old == -1){
      int id = atomicAdd(&ctrl[0], 1);
      if (id < S2CAP){ nodeof[id] = s; sidx[s] = id; }
      else sidx[s] = -1;                    // overflow (won't happen at these sizes)
    }
  }
}

// ---- scan 2: scatter sources into fixed-stride padded CSR (no count/scan passes) ----
__global__ void k_scat(const int* __restrict__ ei, int E,
                       const int* __restrict__ sidx, int* __restrict__ cnt1,
                       int* __restrict__ csr1){
  int e = blockIdx.x*blockDim.x + threadIdx.x;
  if (e >= E) return;
  int sd = sidx[ei[E + e]];
  if (sd >= 0){
    int p = atomicAdd(&cnt1[sd], 1);
    if (p < DEG) csr1[sd*DEG + p] = ei[e];
  }
}

// ---- layer-1 GAT agg at S2 nodes, per (node, head); writes tanh(agg/den + b) ----
__global__ void k_gat1(const float* __restrict__ x, const float* __restrict__ c1W,
                       const float* __restrict__ c1b, const float* __restrict__ AsAd,
                       const int* __restrict__ nodeof, const int* __restrict__ cnt1,
                       const int* __restrict__ csr1, const int* __restrict__ ctrl,
                       float* __restrict__ tbuf){
  int gid = blockIdx.x*blockDim.x + threadIdx.x;
  int sid = gid/6, h = gid - sid*6;
  if (sid >= ctrl[0]) return;
  float Ask[4], Adk[4];
  #pragma unroll
  for (int k = 0; k < 4; ++k){ Ask[k] = AsAd[k*6+h]; Adk[k] = AsAd[24 + k*6 + h]; }
  float W[16][4];
  #pragma unroll
  for (int f = 0; f < 16; ++f)
    #pragma unroll
    for (int k = 0; k < 4; ++k) W[f][k] = c1W[(h*16+f)*4 + k];
  int d = nodeof[sid];
  float4 xd = *(const float4*)(x + 4*(size_t)d);
  float ad = xd.x*Adk[0] + xd.y*Adk[1] + xd.z*Adk[2] + xd.w*Adk[3];
  int beg = sid*DEG, n = cnt1[sid];
  n = (n < DEG) ? n : DEG;
  float den = 0.f, agg[16];
  #pragma unroll
  for (int f = 0; f < 16; ++f) agg[f] = 0.f;
  for (int j = -1; j < n; ++j){            // j==-1: self loop
    int s = (j < 0) ? d : csr1[beg + j];
    float4 xv = *(const float4*)(x + 4*(size_t)s);
    float as = xv.x*Ask[0] + xv.y*Ask[1] + xv.z*Ask[2] + xv.w*Ask[3];
    float wgt = attw(as + ad);
    den += wgt;
    #pragma unroll
    for (int f = 0; f < 16; ++f){
      float h1 = xv.x*W[f][0] + xv.y*W[f][1] + xv.z*W[f][2] + xv.w*W[f][3];
      agg[f] = fmaf(wgt, h1, agg[f]);
    }
  }
  float inv = 1.f/den;
  #pragma unroll
  for (int f = 0; f < 16; ++f)
    tbuf[(size_t)sid*96 + h*16 + f] = ftanh(agg[f]*inv + c1b[h*16+f]);
}

// ---- layer-2 linear + attention scalars fused (32-lane shfl reduce) ----
__global__ void k_h2att(const float* __restrict__ c2W, const float* __restrict__ tbuf,
                        const float* __restrict__ c2as, const float* __restrict__ c2ad,
                        const int* __restrict__ ctrl, float* __restrict__ h2,
                        float* __restrict__ as2, float* __restrict__ ad2){
  int gid = blockIdx.x*blockDim.x + threadIdx.x;
  int sid = gid >> 5, o = gid & 31;
  bool act = sid < ctrl[0];
  float s = 0.f;
  if (act){
    const float* t = tbuf + (size_t)sid*96;
    const float* wr = c2W + o*96;
    #pragma unroll
    for (int j = 0; j < 96; ++j) s = fmaf(wr[j], t[j], s);
    h2[(size_t)sid*32 + o] = s;
  }
  float a = act ? s*c2as[o] : 0.f;
  float b = act ? s*c2ad[o] : 0.f;
  #pragma unroll
  for (int w = 16; w >= 1; w >>= 1){
    a += __shfl_xor(a, w, 32);
    b += __shfl_xor(b, w, 32);
  }
  if (act && o == 0){ as2[sid] = a; ad2[sid] = b; }
}

// ---- layer-2 GAT agg at robots + concat + fc1 + tanh ----
__global__ void k_gat2fc1(const float* __restrict__ h2, const float* __restrict__ as2,
                          const float* __restrict__ ad2, const float* __restrict__ c2b,
                          const float* __restrict__ rf, const float* __restrict__ fc1W,
                          const float* __restrict__ fc1b, const int* __restrict__ sidx,
                          const int* __restrict__ cnt1, const int* __restrict__ csr1,
                          float* __restrict__ xs, int B){
  int rp = blockIdx.x*blockDim.x + threadIdx.x;
  if (rp >= B) return;
  float ad = ad2[rp];
  float den = 0.f, agg[32];
  #pragma unroll
  for (int o = 0; o < 32; ++o) agg[o] = 0.f;
  int beg = rp*DEG, n = cnt1[rp];
  n = (n < DEG) ? n : DEG;
  for (int j = -1; j < n; ++j){
    int ss;
    if (j < 0) ss = rp;                    // self loop (robot's own sid == rp)
    else { int s = csr1[beg + j]; ss = sidx[s]; if (ss < 0 || ss >= S2CAP) continue; }
    float wgt = attw(as2[ss] + ad);
    den += wgt;
    const float* hv = h2 + (size_t)ss*32;
    #pragma unroll
    for (int o = 0; o < 32; ++o) agg[o] = fmaf(wgt, hv[o], agg[o]);
  }
  float inv = 1.f/den;
  float cat[36];
  #pragma unroll
  for (int o = 0; o < 32; ++o) cat[o] = agg[o]*inv + c2b[o];
  #pragma unroll
  for (int k = 0; k < 4; ++k) cat[32+k] = rf[rp*4+k];
  for (int o = 0; o < 64; ++o){
    float s = fc1b[o];
    const float* wrow = fc1W + o*36;
    #pragma unroll
    for (int j = 0; j < 36; ++j) s = fmaf(wrow[j], cat[j], s);
    xs[(size_t)rp*64 + o] = ftanh(s);
  }
}

// ---- GRU input gates for all steps ----
__global__ void k_gi(const float* __restrict__ xs, const float* __restrict__ wih,
                     const float* __restrict__ bih, const float* __restrict__ bhh,
                     float* __restrict__ gi, int B){
  int gid = blockIdx.x*blockDim.x + threadIdx.x;
  if (gid >= B*192) return;
  int t = gid/192, g = gid - t*192;
  const float* xv = xs + (size_t)t*64;
  const float* wr = wih + (size_t)g*64;
  float s = bih[g] + (g < 128 ? bhh[g] : 0.f);
  #pragma unroll
  for (int k = 0; k < 64; ++k) s = fmaf(wr[k], xv[k], s);
  gi[gid] = s;
}

// ---- sequential GRU: 3 waves (r/z/n gate blocks). Weights = 16 NAMED float4
//      vars loaded via asm volatile global_load_dwordx4 — asm results cannot
//      be rematerialized, so they stay VGPR-resident across all 1024 steps.
//      h broadcast via readlane; 1 barrier/step via double-buffered LDS. ----
__global__ __launch_bounds__(192, 1) void k_gru3(const float* __restrict__ gi,
                       const float* __restrict__ whh, const float* __restrict__ bhh,
                       float* __restrict__ ys, int B){
  int tid = threadIdx.x;
  int w = tid >> 6, u = tid & 63, g = tid;      // g = gate-row index in [0,192)
  const float* p = whh + (size_t)g*64;          // lane's own weight row (256 B)
  f32x4 w0,w1,w2,w3,w4,w5,w6,w7,w8,w9,w10,w11,w12,w13,w14,w15;
#define LDW(R, OFF) asm volatile("global_load_dwordx4 %0, %1, off offset:" #OFF : "=v"(R) : "v"(p))
  LDW(w0,0);    LDW(w1,16);   LDW(w2,32);   LDW(w3,48);
  LDW(w4,64);   LDW(w5,80);   LDW(w6,96);   LDW(w7,112);
  LDW(w8,128);  LDW(w9,144);  LDW(w10,160); LDW(w11,176);
  LDW(w12,192); LDW(w13,208); LDW(w14,224); LDW(w15,240);
#undef LDW
  asm volatile("s_waitcnt vmcnt(0)" ::: "memory");
  __builtin_amdgcn_sched_barrier(0);            // rule #18: nothing floats above the wait
  float bb = (w == 2) ? bhh[128 + u] : 0.f;     // bhh_n folded into staged an
  __shared__ float rzbuf[2][256];
  float hvec = 0.f;                              // lane u holds h[u] (all waves)
  float gcur = gi[g];
#define PIN(R) asm volatile("" : "+v"(R))
#define DOT4(W, K)                                                    \
  { float h0_ = __int_as_float(__builtin_amdgcn_readlane(hb, (K)));   \
    float h1_ = __int_as_float(__builtin_amdgcn_readlane(hb, (K)+1)); \
    float h2_ = __int_as_float(__builtin_amdgcn_readlane(hb, (K)+2)); \
    float h3_ = __int_as_float(__builtin_amdgcn_readlane(hb, (K)+3)); \
    a0 = fmaf(W.x, h0_, a0); a1 = fmaf(W.y, h1_, a1);                 \
    a2 = fmaf(W.z, h2_, a2); a3 = fmaf(W.w, h3_, a3); }
  for (int t = 0; t < B; ++t){
    PIN(w0); PIN(w1); PIN(w2);  PIN(w3);  PIN(w4);  PIN(w5);  PIN(w6);  PIN(w7);
    PIN(w8); PIN(w9); PIN(w10); PIN(w11); PIN(w12); PIN(w13); PIN(w14); PIN(w15);
    int tn = (t + 1 < B) ? t + 1 : t;
    float gnext = gi[tn*192 + g];
    float a0 = 0.f, a1 = 0.f, a2 = 0.f, a3 = 0.f;
    int hb = __float_as_int(hvec);
    DOT4(w0,0);   DOT4(w1,4);   DOT4(w2,8);   DOT4(w3,12);
    DOT4(w4,16);  DOT4(w5,20);  DOT4(w6,24);  DOT4(w7,28);
    DOT4(w8,32);  DOT4(w9,36);  DOT4(w10,40); DOT4(w11,44);
    DOT4(w12,48); DOT4(w13,52); DOT4(w14,56); DOT4(w15,60);
    float dot = (a0 + a1) + (a2 + a3);
    float* buf = rzbuf[t & 1];
    if (w < 2){
      buf[w*64 + u] = gcur + dot;               // full pre-activation of r / z
    } else {
      buf[128 + u] = dot + bb;                  // an (recurrent n-term + bhh_n)
      buf[192 + u] = gcur;                      // i_n (input n-term)
    }
    __syncthreads();
    float pre_r = buf[u], pre_z = buf[64 + u], an = buf[128 + u], i_n = buf[192 + u];
    float r  = fsig(pre_r);
    float z  = fsig(pre_z);
    float ng = ftanh(i_n + r*an);
    float hnew = (1.f - z)*ng + z*hvec;
    if (w == 2) ys[(size_t)t*64 + u] = hnew;
    hvec = hnew;
    gcur = gnext;
  }
#undef PIN
#undef DOT4
}

// ---- final fc2 ----
__global__ void k_fc2(const float* __restrict__ ys, const float* __restrict__ f2W,
                      const float* __restrict__ f2b, float* __restrict__ out, int B){
  int gid = blockIdx.x*blockDim.x + threadIdx.x;
  if (gid >= B*11) return;
  int t = gid/11, a = gid - t*11;
  const float* hv = ys + (size_t)t*64;
  const float* wr = f2W + a*64;
  float s = f2b[a];
  #pragma unroll
  for (int k = 0; k < 64; ++k) s = fmaf(wr[k], hv[k], s);
  out[gid] = s;
}

extern "C" void kernel_launch(void* const* d_in, const int* in_sizes, int n_in,
                              void* d_out, int out_size, void* d_ws, size_t ws_size,
                              hipStream_t stream) {
  (void)n_in; (void)out_size; (void)ws_size;
  const float* x    = (const float*)d_in[0];
  const int*   ei   = (const int*)d_in[1];
  const int*   rix  = (const int*)d_in[2];
  const float* rf   = (const float*)d_in[3];
  const float* c1W  = (const float*)d_in[4];
  const float* c1as = (const float*)d_in[5];
  const float* c1ad = (const float*)d_in[6];
  const float* c1b  = (const float*)d_in[7];
  const float* c2W  = (const float*)d_in[8];
  const float* c2as = (const float*)d_in[9];
  const float* c2ad = (const float*)d_in[10];
  const float* c2b  = (const float*)d_in[11];
  const float* fc1W = (const float*)d_in[12];
  const float* fc1b = (const float*)d_in[13];
  const float* wih  = (const float*)d_in[14];
  const float* whh  = (const float*)d_in[15];
  const float* bih  = (const float*)d_in[16];
  const float* bhh  = (const float*)d_in[17];
  const float* f2W  = (const float*)d_in[18];
  const float* f2b  = (const float*)d_in[19];
  float* out = (float*)d_out;

  const int N = in_sizes[0]/4;
  const int E = in_sizes[1]/2;
  const int B = in_sizes[2];

  char* w = (char*)d_ws;
  size_t off = 0;
  auto take = [&](size_t bytes)->char*{
    char* p = w + off;
    off = (off + bytes + 255) & ~(size_t)255;
    return p;
  };
  int*   ctrl   = (int*)  take(256);
  float* AsAd   = (float*)take(256);
  int*   sidx   = (int*)  take((size_t)N*4);
  int*   nodeof = (int*)  take((size_t)S2CAP*4);
  int*   cnt1   = (int*)  take((size_t)S2CAP*4);
  int*   csr1   = (int*)  take((size_t)S2CAP*DEG*4);
  float* tbuf   = (float*)take((size_t)S2CAP*96*4);
  float* h2     = (float*)take((size_t)S2CAP*32*4);
  float* as2    = (float*)take((size_t)S2CAP*4);
  float* ad2    = (float*)take((size_t)S2CAP*4);
  float* xs     = (float*)take((size_t)B*64*4);
  float* gi     = (float*)take((size_t)B*192*4);
  float* ys     = (float*)take((size_t)B*64*4);

  hipMemsetAsync(sidx, 0xFF, (size_t)N*4, stream);       // -1

  k_init   <<<(S2CAP+255)/256, 256, 0, stream>>>(c1W, c1as, c1ad, AsAd, rix, B, sidx, nodeof, ctrl, cnt1);
  k_claim  <<<(E+255)/256, 256, 0, stream>>>(ei, E, B, sidx, nodeof, ctrl);
  k_scat   <<<(E+255)/256, 256, 0, stream>>>(ei, E, sidx, cnt1, csr1);
  k_gat1   <<<(S2CAP*6+255)/256, 256, 0, stream>>>(x, c1W, c1b, AsAd, nodeof, cnt1, csr1, ctrl, tbuf);
  k_h2att  <<<(S2CAP*32+255)/256, 256, 0, stream>>>(c2W, tbuf, c2as, c2ad, ctrl, h2, as2, ad2);
  k_gat2fc1<<<(B+255)/256, 256, 0, stream>>>(h2, as2, ad2, c2b, rf, fc1W, fc1b, sidx, cnt1, csr1, xs, B);
  k_gi     <<<(B*192+255)/256, 256, 0, stream>>>(xs, wih, bih, bhh, gi, B);
  k_gru3   <<<1, 192, 0, stream>>>(gi, whh, bhh, ys, B);
  k_fc2    <<<(B*11+255)/256, 256, 0, stream>>>(ys, f2W, f2b, out, B);
}

// Round 6
// 931.366 us; speedup vs baseline: 1.0309x; 1.0309x over previous
//
#include <hip/hip_runtime.h>

#define S2CAP 24576   // cap on |S2| (robots + sources of robot in-edges); expected ~17.4K
#define DEG   96      // padded per-node in-degree cap (Poisson(16): P(>96) ~ 1e-40)
#define CH    16      // GRU steps per staged gi chunk

typedef float f32x4 __attribute__((ext_vector_type(4)));

__device__ __forceinline__ float fsig(float x){ return 1.f/(1.f + __expf(-x)); }
__device__ __forceinline__ float ftanh(float a){
  a = fminf(fmaxf(a, -15.f), 15.f);
  float e2 = __expf(2.f*a);
  return (e2 - 1.f)/(e2 + 1.f);
}
__device__ __forceinline__ float attw(float e){        // leaky_relu(0.2) then exp (no max-sub)
  e = (e > 0.f) ? e : 0.2f*e;
  return __expf(e);
}

// ---- fused init: AsAd precompute + robot flag + cnt1 zero + ctrl ----
// (sidx was memset to -1 earlier in the stream)
__global__ void k_init(const float* __restrict__ c1W, const float* __restrict__ c1as,
                       const float* __restrict__ c1ad, float* __restrict__ AsAd,
                       const int* __restrict__ rix, int B, int* __restrict__ sidx,
                       int* __restrict__ nodeof, int* __restrict__ ctrl,
                       int* __restrict__ cnt1){
  int gid = blockIdx.x*blockDim.x + threadIdx.x;
  if (gid == 0) ctrl[0] = B;
  if (gid < 48){
    int which = gid/24, r = gid%24, k = r/6, h = r%6;
    const float* av = which ? c1ad : c1as;
    float s = 0.f;
    for (int f = 0; f < 16; ++f) s += c1W[(h*16+f)*4 + k] * av[h*16+f];
    AsAd[which*24 + k*6 + h] = s;
  }
  if (gid < B){ int r = rix[gid]; sidx[r] = gid; nodeof[gid] = r; }
  if (gid < S2CAP) cnt1[gid] = 0;
}

// ---- scan 1: claim sources of edges into robots ----
__global__ void k_claim(const int* __restrict__ ei, int E, int B,
                        int* __restrict__ sidx, int* __restrict__ nodeof,
                        int* __restrict__ ctrl){
  int e = blockIdx.x*blockDim.x + threadIdx.x;
  if (e >= E) return;
  int d = ei[E + e];
  int sd = sidx[d];
  if (sd < 0 || sd >= B) return;           // dst not a robot
  int s = ei[e];
  if (sidx[s] < 0){
    int old = atomicCAS(&sidx[s], -1, -2);
    if (old == -1){
      int id = atomicAdd(&ctrl[0], 1);
      if (id < S2CAP){ nodeof[id] = s; sidx[s] = id; }
      else sidx[s] = -1;                    // overflow (won't happen at these sizes)
    }
  }
}

// ---- scan 2: scatter sources into fixed-stride padded CSR (no count/scan passes) ----
__global__ void k_scat(const int* __restrict__ ei, int E,
                       const int* __restrict__ sidx, int* __restrict__ cnt1,
                       int* __restrict__ csr1){
  int e = blockIdx.x*blockDim.x + threadIdx.x;
  if (e >= E) return;
  int sd = sidx[ei[E + e]];
  if (sd >= 0){
    int p = atomicAdd(&cnt1[sd], 1);
    if (p < DEG) csr1[sd*DEG + p] = ei[e];
  }
}

// ---- layer-1 GAT agg at S2 nodes, per (node, head); writes tanh(agg/den + b) ----
__global__ void k_gat1(const float* __restrict__ x, const float* __restrict__ c1W,
                       const float* __restrict__ c1b, const float* __restrict__ AsAd,
                       const int* __restrict__ nodeof, const int* __restrict__ cnt1,
                       const int* __restrict__ csr1, const int* __restrict__ ctrl,
                       float* __restrict__ tbuf){
  int gid = blockIdx.x*blockDim.x + threadIdx.x;
  int sid = gid/6, h = gid - sid*6;
  if (sid >= ctrl[0]) return;
  float Ask[4], Adk[4];
  #pragma unroll
  for (int k = 0; k < 4; ++k){ Ask[k] = AsAd[k*6+h]; Adk[k] = AsAd[24 + k*6 + h]; }
  float W[16][4];
  #pragma unroll
  for (int f = 0; f < 16; ++f)
    #pragma unroll
    for (int k = 0; k < 4; ++k) W[f][k] = c1W[(h*16+f)*4 + k];
  int d = nodeof[sid];
  float4 xd = *(const float4*)(x + 4*(size_t)d);
  float ad = xd.x*Adk[0] + xd.y*Adk[1] + xd.z*Adk[2] + xd.w*Adk[3];
  int beg = sid*DEG, n = cnt1[sid];
  n = (n < DEG) ? n : DEG;
  float den = 0.f, agg[16];
  #pragma unroll
  for (int f = 0; f < 16; ++f) agg[f] = 0.f;
  for (int j = -1; j < n; ++j){            // j==-1: self loop
    int s = (j < 0) ? d : csr1[beg + j];
    float4 xv = *(const float4*)(x + 4*(size_t)s);
    float as = xv.x*Ask[0] + xv.y*Ask[1] + xv.z*Ask[2] + xv.w*Ask[3];
    float wgt = attw(as + ad);
    den += wgt;
    #pragma unroll
    for (int f = 0; f < 16; ++f){
      float h1 = xv.x*W[f][0] + xv.y*W[f][1] + xv.z*W[f][2] + xv.w*W[f][3];
      agg[f] = fmaf(wgt, h1, agg[f]);
    }
  }
  float inv = 1.f/den;
  #pragma unroll
  for (int f = 0; f < 16; ++f)
    tbuf[(size_t)sid*96 + h*16 + f] = ftanh(agg[f]*inv + c1b[h*16+f]);
}

// ---- layer-2 linear + attention scalars fused (32-lane shfl reduce) ----
__global__ void k_h2att(const float* __restrict__ c2W, const float* __restrict__ tbuf,
                        const float* __restrict__ c2as, const float* __restrict__ c2ad,
                        const int* __restrict__ ctrl, float* __restrict__ h2,
                        float* __restrict__ as2, float* __restrict__ ad2){
  int gid = blockIdx.x*blockDim.x + threadIdx.x;
  int sid = gid >> 5, o = gid & 31;
  bool act = sid < ctrl[0];
  float s = 0.f;
  if (act){
    const float* t = tbuf + (size_t)sid*96;
    const float* wr = c2W + o*96;
    #pragma unroll
    for (int j = 0; j < 96; ++j) s = fmaf(wr[j], t[j], s);
    h2[(size_t)sid*32 + o] = s;
  }
  float a = act ? s*c2as[o] : 0.f;
  float b = act ? s*c2ad[o] : 0.f;
  #pragma unroll
  for (int w = 16; w >= 1; w >>= 1){
    a += __shfl_xor(a, w, 32);
    b += __shfl_xor(b, w, 32);
  }
  if (act && o == 0){ as2[sid] = a; ad2[sid] = b; }
}

// ---- layer-2 GAT agg at robots + concat + fc1 + tanh ----
__global__ void k_gat2fc1(const float* __restrict__ h2, const float* __restrict__ as2,
                          const float* __restrict__ ad2, const float* __restrict__ c2b,
                          const float* __restrict__ rf, const float* __restrict__ fc1W,
                          const float* __restrict__ fc1b, const int* __restrict__ sidx,
                          const int* __restrict__ cnt1, const int* __restrict__ csr1,
                          float* __restrict__ xs, int B){
  int rp = blockIdx.x*blockDim.x + threadIdx.x;
  if (rp >= B) return;
  float ad = ad2[rp];
  float den = 0.f, agg[32];
  #pragma unroll
  for (int o = 0; o < 32; ++o) agg[o] = 0.f;
  int beg = rp*DEG, n = cnt1[rp];
  n = (n < DEG) ? n : DEG;
  for (int j = -1; j < n; ++j){
    int ss;
    if (j < 0) ss = rp;                    // self loop (robot's own sid == rp)
    else { int s = csr1[beg + j]; ss = sidx[s]; if (ss < 0 || ss >= S2CAP) continue; }
    float wgt = attw(as2[ss] + ad);
    den += wgt;
    const float* hv = h2 + (size_t)ss*32;
    #pragma unroll
    for (int o = 0; o < 32; ++o) agg[o] = fmaf(wgt, hv[o], agg[o]);
  }
  float inv = 1.f/den;
  float cat[36];
  #pragma unroll
  for (int o = 0; o < 32; ++o) cat[o] = agg[o]*inv + c2b[o];
  #pragma unroll
  for (int k = 0; k < 4; ++k) cat[32+k] = rf[rp*4+k];
  for (int o = 0; o < 64; ++o){
    float s = fc1b[o];
    const float* wrow = fc1W + o*36;
    #pragma unroll
    for (int j = 0; j < 36; ++j) s = fmaf(wrow[j], cat[j], s);
    xs[(size_t)rp*64 + o] = ftanh(s);
  }
}

// ---- GRU input gates for all steps ----
__global__ void k_gi(const float* __restrict__ xs, const float* __restrict__ wih,
                     const float* __restrict__ bih, const float* __restrict__ bhh,
                     float* __restrict__ gi, int B){
  int gid = blockIdx.x*blockDim.x + threadIdx.x;
  if (gid >= B*192) return;
  int t = gid/192, g = gid - t*192;
  const float* xv = xs + (size_t)t*64;
  const float* wr = wih + (size_t)g*64;
  float s = bih[g] + (g < 128 ? bhh[g] : 0.f);
  #pragma unroll
  for (int k = 0; k < 64; ++k) s = fmaf(wr[k], xv[k], s);
  gi[gid] = s;
}

// ---- sequential GRU: 3 waves (r/z/n gate blocks). Weights via asm
//      global_load_dwordx4 into 16 named float4s. gi staged into LDS in
//      CH-step chunks (triple buffer, distance-2 prefetch) via
//      global_load_lds — per-step gi read is a conflict-free ds_read
//      instead of an exposed cross-XCD global load. ----
__global__ __launch_bounds__(192, 1) void k_gru3(const float* __restrict__ gi,
                       const float* __restrict__ whh, const float* __restrict__ bhh,
                       float* __restrict__ ys, int B){
  int tid = threadIdx.x;
  int w = tid >> 6, u = tid & 63, g = tid;      // g = gate-row index in [0,192)
  const float* p = whh + (size_t)g*64;          // lane's own weight row (256 B)
  f32x4 w0,w1,w2,w3,w4,w5,w6,w7,w8,w9,w10,w11,w12,w13,w14,w15;
#define LDW(R, OFF) asm volatile("global_load_dwordx4 %0, %1, off offset:" #OFF : "=v"(R) : "v"(p))
  LDW(w0,0);    LDW(w1,16);   LDW(w2,32);   LDW(w3,48);
  LDW(w4,64);   LDW(w5,80);   LDW(w6,96);   LDW(w7,112);
  LDW(w8,128);  LDW(w9,144);  LDW(w10,160); LDW(w11,176);
  LDW(w12,192); LDW(w13,208); LDW(w14,224); LDW(w15,240);
#undef LDW
  asm volatile("s_waitcnt vmcnt(0)" ::: "memory");
  __builtin_amdgcn_sched_barrier(0);            // rule #18: nothing floats above the wait
  float bb = (w == 2) ? bhh[128 + u] : 0.f;     // bhh_n folded into staged an

  __shared__ float gbuf[3][CH*192];             // 3 x 12 KB staged gi chunks
  __shared__ float rzbuf[2][256];
  int nch = (B + CH - 1)/CH;

  // wave-cooperative stage: wave w covers floats [w*1024, w*1024+1024) of the
  // chunk; 4 issues of 1KB (64 lanes x 16B), LDS dst wave-uniform + lane*16.
  auto stage = [&](int cbuf, int chunk){
    if (chunk >= nch) return;
    const float* gb = gi + (size_t)chunk*(CH*192) + w*1024 + u*4;
    float* lb = &gbuf[cbuf][w*1024];
    __builtin_amdgcn_global_load_lds(
      (const __attribute__((address_space(1))) unsigned int*)(gb),
      (__attribute__((address_space(3))) unsigned int*)(lb), 16, 0, 0);
    __builtin_amdgcn_global_load_lds(
      (const __attribute__((address_space(1))) unsigned int*)(gb + 256),
      (__attribute__((address_space(3))) unsigned int*)(lb + 256), 16, 0, 0);
    __builtin_amdgcn_global_load_lds(
      (const __attribute__((address_space(1))) unsigned int*)(gb + 512),
      (__attribute__((address_space(3))) unsigned int*)(lb + 512), 16, 0, 0);
    __builtin_amdgcn_global_load_lds(
      (const __attribute__((address_space(1))) unsigned int*)(gb + 768),
      (__attribute__((address_space(3))) unsigned int*)(lb + 768), 16, 0, 0);
  };

  stage(0, 0);
  stage(1, 1);

  float hvec = 0.f, gcur = 0.f;
#define PIN(R) asm volatile("" : "+v"(R))
#define DOT4(W, K)                                                    \
  { float h0_ = __int_as_float(__builtin_amdgcn_readlane(hb, (K)));   \
    float h1_ = __int_as_float(__builtin_amdgcn_readlane(hb, (K)+1)); \
    float h2_ = __int_as_float(__builtin_amdgcn_readlane(hb, (K)+2)); \
    float h3_ = __int_as_float(__builtin_amdgcn_readlane(hb, (K)+3)); \
    a0 = fmaf(W.x, h0_, a0); a1 = fmaf(W.y, h1_, a1);                 \
    a2 = fmaf(W.z, h2_, a2); a3 = fmaf(W.w, h3_, a3); }

  int cbx = 0;
  for (int c = 0; c < nch; ++c){
    int nbx = cbx + 1; if (nbx == 3) nbx = 0;
    int sbx = nbx + 1; if (sbx == 3) sbx = 0;   // (c+2)%3
    // drain outstanding stagings (chunk c and c+1 issued >= 1 chunk ago),
    // make them visible to all waves, then kick off chunk c+2.
    asm volatile("s_waitcnt vmcnt(0)" ::: "memory");
    __syncthreads();
    stage(sbx, c + 2);
    if (c == 0) gcur = gbuf[0][g];
    int lim = B - c*CH; if (lim > CH) lim = CH;
    for (int ti = 0; ti < lim; ++ti){
      int t = c*CH + ti;
      PIN(w0); PIN(w1); PIN(w2);  PIN(w3);  PIN(w4);  PIN(w5);  PIN(w6);  PIN(w7);
      PIN(w8); PIN(w9); PIN(w10); PIN(w11); PIN(w12); PIN(w13); PIN(w14); PIN(w15);
      // prefetch next step's gi element from LDS (crosses into next chunk's
      // buffer on the last step; that buffer was staged a full chunk ago)
      float gnext = (ti + 1 < CH) ? gbuf[cbx][(ti+1)*192 + g] : gbuf[nbx][g];
      float a0 = 0.f, a1 = 0.f, a2 = 0.f, a3 = 0.f;
      int hb = __float_as_int(hvec);
      DOT4(w0,0);   DOT4(w1,4);   DOT4(w2,8);   DOT4(w3,12);
      DOT4(w4,16);  DOT4(w5,20);  DOT4(w6,24);  DOT4(w7,28);
      DOT4(w8,32);  DOT4(w9,36);  DOT4(w10,40); DOT4(w11,44);
      DOT4(w12,48); DOT4(w13,52); DOT4(w14,56); DOT4(w15,60);
      float dot = (a0 + a1) + (a2 + a3);
      float* buf = rzbuf[t & 1];
      if (w < 2){
        buf[w*64 + u] = gcur + dot;             // full pre-activation of r / z
      } else {
        buf[128 + u] = dot + bb;                // an (recurrent n-term + bhh_n)
        buf[192 + u] = gcur;                    // i_n (input n-term)
      }
      __syncthreads();
      float pre_r = buf[u], pre_z = buf[64 + u], an = buf[128 + u], i_n = buf[192 + u];
      float r  = fsig(pre_r);
      float z  = fsig(pre_z);
      float ng = ftanh(i_n + r*an);
      float hnew = (1.f - z)*ng + z*hvec;
      if (w == 2) ys[(size_t)t*64 + u] = hnew;
      hvec = hnew;
      gcur = gnext;
    }
    cbx = nbx;
  }
#undef PIN
#undef DOT4
}

// ---- final fc2 ----
__global__ void k_fc2(const float* __restrict__ ys, const float* __restrict__ f2W,
                      const float* __restrict__ f2b, float* __restrict__ out, int B){
  int gid = blockIdx.x*blockDim.x + threadIdx.x;
  if (gid >= B*11) return;
  int t = gid/11, a = gid - t*11;
  const float* hv = ys + (size_t)t*64;
  const float* wr = f2W + a*64;
  float s = f2b[a];
  #pragma unroll
  for (int k = 0; k < 64; ++k) s = fmaf(wr[k], hv[k], s);
  out[gid] = s;
}

extern "C" void kernel_launch(void* const* d_in, const int* in_sizes, int n_in,
                              void* d_out, int out_size, void* d_ws, size_t ws_size,
                              hipStream_t stream) {
  (void)n_in; (void)out_size; (void)ws_size;
  const float* x    = (const float*)d_in[0];
  const int*   ei   = (const int*)d_in[1];
  const int*   rix  = (const int*)d_in[2];
  const float* rf   = (const float*)d_in[3];
  const float* c1W  = (const float*)d_in[4];
  const float* c1as = (const float*)d_in[5];
  const float* c1ad = (const float*)d_in[6];
  const float* c1b  = (const float*)d_in[7];
  const float* c2W  = (const float*)d_in[8];
  const float* c2as = (const float*)d_in[9];
  const float* c2ad = (const float*)d_in[10];
  const float* c2b  = (const float*)d_in[11];
  const float* fc1W = (const float*)d_in[12];
  const float* fc1b = (const float*)d_in[13];
  const float* wih  = (const float*)d_in[14];
  const float* whh  = (const float*)d_in[15];
  const float* bih  = (const float*)d_in[16];
  const float* bhh  = (const float*)d_in[17];
  const float* f2W  = (const float*)d_in[18];
  const float* f2b  = (const float*)d_in[19];
  float* out = (float*)d_out;

  const int N = in_sizes[0]/4;
  const int E = in_sizes[1]/2;
  const int B = in_sizes[2];

  char* w = (char*)d_ws;
  size_t off = 0;
  auto take = [&](size_t bytes)->char*{
    char* p = w + off;
    off = (off + bytes + 255) & ~(size_t)255;
    return p;
  };
  int*   ctrl   = (int*)  take(256);
  float* AsAd   = (float*)take(256);
  int*   sidx   = (int*)  take((size_t)N*4);
  int*   nodeof = (int*)  take((size_t)S2CAP*4);
  int*   cnt1   = (int*)  take((size_t)S2CAP*4);
  int*   csr1   = (int*)  take((size_t)S2CAP*DEG*4);
  float* tbuf   = (float*)take((size_t)S2CAP*96*4);
  float* h2     = (float*)take((size_t)S2CAP*32*4);
  float* as2    = (float*)take((size_t)S2CAP*4);
  float* ad2    = (float*)take((size_t)S2CAP*4);
  float* xs     = (float*)take((size_t)B*64*4);
  float* gi     = (float*)take((size_t)B*192*4);
  float* ys     = (float*)take((size_t)B*64*4);

  hipMemsetAsync(sidx, 0xFF, (size_t)N*4, stream);       // -1

  k_init   <<<(S2CAP+255)/256, 256, 0, stream>>>(c1W, c1as, c1ad, AsAd, rix, B, sidx, nodeof, ctrl, cnt1);
  k_claim  <<<(E+255)/256, 256, 0, stream>>>(ei, E, B, sidx, nodeof, ctrl);
  k_scat   <<<(E+255)/256, 256, 0, stream>>>(ei, E, sidx, cnt1, csr1);
  k_gat1   <<<(S2CAP*6+255)/256, 256, 0, stream>>>(x, c1W, c1b, AsAd, nodeof, cnt1, csr1, ctrl, tbuf);
  k_h2att  <<<(S2CAP*32+255)/256, 256, 0, stream>>>(c2W, tbuf, c2as, c2ad, ctrl, h2, as2, ad2);
  k_gat2fc1<<<(B+255)/256, 256, 0, stream>>>(h2, as2, ad2, c2b, rf, fc1W, fc1b, sidx, cnt1, csr1, xs, B);
  k_gi     <<<(B*192+255)/256, 256, 0, stream>>>(xs, wih, bih, bhh, gi, B);
  k_gru3   <<<1, 192, 0, stream>>>(gi, whh, bhh, ys, B);
  k_fc2    <<<(B*11+255)/256, 256, 0, stream>>>(ys, f2W, f2b, out, B);
}